// Round 10
// baseline (458.123 us; speedup 1.0000x reference)
//
#include <hip/hip_runtime.h>
#include <hip/hip_bf16.h>

typedef __hip_bfloat16 bf16;
typedef short bf16x8 __attribute__((ext_vector_type(8)));   // 8 bf16 = 16B (4 VGPRs)
typedef float f32x4 __attribute__((ext_vector_type(4)));

#define ND     40962
#define NUP    163842
#define NBATCH 2
#define NTC    2561            // ceil(NUP/64)
#define BN_EPS 1e-5
#define SLOPE  0.2f

// ---- ws layout (bytes) ----
#define OFF_W1P   0ull                      // 64*896*2  = 114688
#define OFF_W2P   114688ull                 // 64*448*2  = 57344
#define OFF_STATS 172032ull                 // sc[64]+sh[64] fp32
#define OFF_H     173056ull                 // h bf16: 2*40962*64*2 = 10486272 ; partials alias
#define OFF_P2    (OFF_H + 2622464ull)      // p2 (8KB) aliases h tail
#define OFF_HM    10659328ull               // hm bf16: 2*163842*64*2 = 41943552 ; y2 aliases
#define OFF_X2T   52602880ull               // x2t bf16: 41943552
#define OFF_Y     94546432ull               // y bf16: 41943552
// total ≈ 136.5 MB

__device__ __forceinline__ void gload_lds16(const void* g, void* l) {
  __builtin_amdgcn_global_load_lds(
      (const __attribute__((address_space(1))) void*)g,
      (__attribute__((address_space(3))) void*)l, 16, 0, 0);
}

__device__ __forceinline__ float lrelu(float v) { return v >= 0.0f ? v : SLOPE * v; }

// ---------------- K1: h[b,n,o] (bf16 node-major) + fused weight-permute blocks ---------------
// blocks x<641: h; blocks x>=641 (y==0): permute conv weights f' = kk*C + c, bf16-convert.
__global__ __launch_bounds__(256) void k_h(const float* __restrict__ x1,
                                           const float* __restrict__ wfc,
                                           const float* __restrict__ bfc,
                                           bf16* __restrict__ h,
                                           const float* __restrict__ w1,
                                           const float* __restrict__ w2,
                                           bf16* __restrict__ w1p, bf16* __restrict__ w2p) {
  int bx = blockIdx.x;
  if (bx >= 641) {
    if (blockIdx.y == 0) {
      int t = (bx - 641) * 256 + threadIdx.x;
      if (t < 64 * 896) {
        int o = t / 896, f = t % 896;
        int kk = f / 128, c = f % 128;
        w1p[t] = __float2bfloat16(w1[o * 896 + c * 7 + kk]);
      } else if (t < 64 * 896 + 64 * 448) {
        int idx = t - 64 * 896;
        int o = idx / 448, f = idx % 448;
        int kk = f / 64, c = f % 64;
        w2p[idx] = __float2bfloat16(w2[o * 448 + c * 7 + kk]);
      }
    }
    return;
  }
  __shared__ float wl[128 * 64];   // wl[c*64+o]
  __shared__ float bl[64];
  int tid = threadIdx.x, b = blockIdx.y;
  for (int i = tid; i < 8192; i += 256) { int o = i >> 7, c = i & 127; wl[c * 64 + o] = wfc[i]; }
  if (tid < 64) bl[tid] = bfc[tid];
  __syncthreads();
  int ln = tid & 63, wv = tid >> 6;          // node-lane, out-group (wave-uniform)
  int n = bx * 64 + ln;
  int nc = n < ND ? n : ND - 1;
  float acc[16];
#pragma unroll
  for (int j = 0; j < 16; ++j) acc[j] = bl[wv * 16 + j];
#pragma unroll 4
  for (int c = 0; c < 128; ++c) {
    float xv = x1[((size_t)b * 128 + c) * (size_t)ND + nc];
    const f32x4* wrow = (const f32x4*)(wl + c * 64 + wv * 16);   // wave-uniform -> broadcast
#pragma unroll
    for (int g = 0; g < 4; ++g) {
      f32x4 wvv = wrow[g];
      acc[g * 4 + 0] = fmaf(xv, wvv[0], acc[g * 4 + 0]);
      acc[g * 4 + 1] = fmaf(xv, wvv[1], acc[g * 4 + 1]);
      acc[g * 4 + 2] = fmaf(xv, wvv[2], acc[g * 4 + 2]);
      acc[g * 4 + 3] = fmaf(xv, wvv[3], acc[g * 4 + 3]);
    }
  }
  if (n < ND) {
    bf16* hp = h + ((size_t)b * ND + n) * 64 + wv * 16;
#pragma unroll
    for (int og = 0; og < 2; ++og) {
      union { bf16x8 v; bf16 e[8]; } u;
#pragma unroll
      for (int j = 0; j < 8; ++j) u.e[j] = __float2bfloat16(acc[og * 8 + j]);
      ((bf16x8*)hp)[og] = u.v;
    }
  }
}

// ---------------- K2: prep — hm[b,m,:]=0.5*(h[up0]+h[up1]) AND x2t[b,m,c]=bf16(x2[b,c,m]) ----
__global__ __launch_bounds__(256) void k_prep(const float* __restrict__ x2,
                                              const bf16* __restrict__ h,
                                              const int* __restrict__ upn,
                                              bf16* __restrict__ hm,
                                              bf16* __restrict__ x2t) {
  __shared__ float tt[64][65];
  __shared__ int un[64][2];
  int tid = threadIdx.x, b = blockIdx.y;
  int m0 = blockIdx.x * 64;
  if (m0 + 64 <= NUP) {
    // fast path: f32x4 loads (16B/lane)
    int mq = tid & 15;
#pragma unroll
    for (int i = 0; i < 4; ++i) {
      int c = i * 16 + (tid >> 4);
      f32x4 v = *(const f32x4*)(x2 + ((size_t)b * 64 + c) * (size_t)NUP + m0 + mq * 4);
      tt[c][mq * 4 + 0] = v[0]; tt[c][mq * 4 + 1] = v[1];
      tt[c][mq * 4 + 2] = v[2]; tt[c][mq * 4 + 3] = v[3];
    }
  } else {
#pragma unroll
    for (int i = 0; i < 16; ++i) {
      int c = i * 4 + (tid >> 6);
      int ml = tid & 63;
      int m = m0 + ml; if (m >= NUP) m = NUP - 1;
      tt[c][ml] = x2[((size_t)b * 64 + c) * (size_t)NUP + m];
    }
  }
  if (tid < 128) {
    int ml = tid >> 1, w = tid & 1;
    int m = m0 + ml; if (m >= NUP) m = NUP - 1;
    un[ml][w] = upn[(size_t)m * 2 + w];
  }
  __syncthreads();
  int ln = tid >> 2, p = tid & 3;            // 4 threads per node, 32B seg each
  int m = m0 + ln;
  if (m >= NUP) return;
  // hm part
  {
    const bf16* h0 = h + ((size_t)b * ND + un[ln][0]) * 64 + p * 16;
    const bf16* h1 = h + ((size_t)b * ND + un[ln][1]) * 64 + p * 16;
    bf16* d = hm + ((size_t)b * NUP + m) * 64 + p * 16;
#pragma unroll
    for (int q = 0; q < 2; ++q) {
      union { bf16x8 v; bf16 e[8]; } a, bb, o_;
      a.v = ((const bf16x8*)h0)[q];
      bb.v = ((const bf16x8*)h1)[q];
#pragma unroll
      for (int j = 0; j < 8; ++j)
        o_.e[j] = __float2bfloat16(0.5f * (__bfloat162float(a.e[j]) + __bfloat162float(bb.e[j])));
      ((bf16x8*)d)[q] = o_.v;
    }
  }
  // x2t part
  {
    bf16* d = x2t + ((size_t)b * NUP + m) * 64 + p * 16;
#pragma unroll
    for (int q = 0; q < 2; ++q) {
      union { bf16x8 v; bf16 e[8]; } o_;
#pragma unroll
      for (int j = 0; j < 8; ++j) o_.e[j] = __float2bfloat16(tt[p * 16 + q * 8 + j][ln]);
      ((bf16x8*)d)[q] = o_.v;
    }
  }
}

// ---------------- K3: conv1 — 64ch (128B-row) steps, A+W DMA dbuf, 1 barrier/step ------------
// Step t: kk = t>>1, half = t&1 (0 -> hm, 1 -> x2t). Requests are 8-lane 128B (L2 line).
__global__ __launch_bounds__(256, 4) void k_conv1(const bf16* __restrict__ hm,
                                                  const bf16* __restrict__ x2t,
                                                  const int* __restrict__ neigh,
                                                  const bf16* __restrict__ wp,
                                                  const float* __restrict__ bias,
                                                  bf16* __restrict__ y,
                                                  float* __restrict__ partials) {
  constexpr int NSTEP = 14;
  __shared__ bf16 lA[2][64 * 64];            // 8KB each
  __shared__ bf16 lW[2][64 * 64];
  __shared__ int nbl[448];

  int tid = threadIdx.x, b = blockIdx.y;
  int n0 = blockIdx.x * 64;
  int wv = tid >> 6, lane = tid & 63;
  int l15 = lane & 15, l4 = lane >> 4;

  for (int j = tid; j < 448; j += 256) {
    int gi = n0 * 7 + j;
    int gmax = NUP * 7 - 1;
    nbl[j] = neigh[gi <= gmax ? gi : gmax];
  }

  f32x4 acc[4];
#pragma unroll
  for (int ot = 0; ot < 4; ++ot) {
    float bv = bias[ot * 16 + l15];
    acc[ot] = (f32x4){bv, bv, bv, bv};
  }

  const bf16* hmb  = hm  + (size_t)b * NUP * 64;
  const bf16* x2tb = x2t + (size_t)b * NUP * 64;
  const int lrow = lane >> 3;                // row within instr
  const int g    = ((lane & 7) ^ lrow) * 8;  // pre-swizzled slot (elems), row&7 == lrow

  auto STAGE = [&](int buf, int t) {
    int kk = t >> 1;
    const bf16* src = (t & 1) ? x2tb : hmb;
#pragma unroll
    for (int i = 0; i < 2; ++i) {
      int srow = wv * 16 + i * 8 + lrow;
      int node = nbl[srow * 7 + kk];
      gload_lds16(src + (size_t)node * 64 + g, &lA[buf][(wv * 16 + i * 8) * 64]);
      gload_lds16(wp + (size_t)srow * 896 + t * 64 + g, &lW[buf][(wv * 16 + i * 8) * 64]);
    }
  };

  const int r = wv * 16 + l15;

  __syncthreads();                           // nbl ready
  STAGE(0, 0);
  __syncthreads();                           // step 0 staged (implicit vmcnt(0))

  int buf = 0;
#pragma unroll
  for (int t = 0; t < NSTEP; ++t) {
    if (t + 1 < NSTEP) STAGE(buf ^ 1, t + 1);
#pragma unroll
    for (int ks = 0; ks < 2; ++ks) {
      int sa = ks * 4 + l4;                  // 0..7
      bf16x8 a = *(const bf16x8*)(&lA[buf][r * 64 + ((sa ^ (r & 7)) * 8)]);
#pragma unroll
      for (int ot = 0; ot < 4; ++ot) {
        int o = ot * 16 + l15;
        bf16x8 bb = *(const bf16x8*)(&lW[buf][o * 64 + ((sa ^ (o & 7)) * 8)]);
        acc[ot] = __builtin_amdgcn_mfma_f32_16x16x32_bf16(a, bb, acc[ot], 0, 0, 0);
      }
    }
    __syncthreads();
    buf ^= 1;
  }

  float* lred = (float*)&lA[0][0];
  float s[4], q[4];
#pragma unroll
  for (int ot = 0; ot < 4; ++ot) { s[ot] = 0.0f; q[ot] = 0.0f; }
  bf16* yb = y + (size_t)b * NUP * 64;
  int nodebase = n0 + wv * 16 + l4 * 4;
#pragma unroll
  for (int i = 0; i < 4; ++i) {
    int node = nodebase + i;
    bool ok = node < NUP;
#pragma unroll
    for (int ot = 0; ot < 4; ++ot) {
      float v = acc[ot][i];
      if (ok) {
        yb[(size_t)node * 64 + ot * 16 + l15] = __float2bfloat16(v);
        s[ot] += v; q[ot] += v * v;
      }
    }
  }
#pragma unroll
  for (int ot = 0; ot < 4; ++ot) {
    s[ot] += __shfl_xor(s[ot], 16); s[ot] += __shfl_xor(s[ot], 32);
    q[ot] += __shfl_xor(q[ot], 16); q[ot] += __shfl_xor(q[ot], 32);
  }
  if (lane < 16) {
#pragma unroll
    for (int ot = 0; ot < 4; ++ot) {
      lred[(wv * 2 + 0) * 64 + ot * 16 + lane] = s[ot];
      lred[(wv * 2 + 1) * 64 + ot * 16 + lane] = q[ot];
    }
  }
  __syncthreads();
  if (tid < 128) {
    int which = tid >> 6, c = tid & 63;
    float p = lred[(0 * 2 + which) * 64 + c] + lred[(1 * 2 + which) * 64 + c] +
              lred[(2 * 2 + which) * 64 + c] + lred[(3 * 2 + which) * 64 + c];
    partials[((size_t)b * gridDim.x + blockIdx.x) * 128 + which * 64 + c] = p;
  }
}

// ---------------- K5: conv2 — full-kk steps; BN1+lrelu fused reg-staged A (padded, 1-buf) ----
__global__ __launch_bounds__(256, 6) void k_conv2(const bf16* __restrict__ y,
                                                  const int* __restrict__ neigh,
                                                  const bf16* __restrict__ wp,
                                                  const float* __restrict__ bias,
                                                  const float* __restrict__ sc,
                                                  const float* __restrict__ sh,
                                                  bf16* __restrict__ y2,
                                                  float* __restrict__ partials) {
  constexpr int NSTEP = 7;
  __shared__ bf16 lA[64 * 66];               // padded rows: stride 132B
  __shared__ bf16 lW[2][64 * 64];
  __shared__ int nbl[448];
  __shared__ float ssc[64], ssh[64];

  int tid = threadIdx.x, b = blockIdx.y;
  int n0 = blockIdx.x * 64;
  int wv = tid >> 6, lane = tid & 63;
  int l15 = lane & 15, l4 = lane >> 4;

  for (int j = tid; j < 448; j += 256) {
    int gi = n0 * 7 + j;
    int gmax = NUP * 7 - 1;
    nbl[j] = neigh[gi <= gmax ? gi : gmax];
  }
  if (tid < 64) { ssc[tid] = sc[tid]; ssh[tid] = sh[tid]; }

  f32x4 acc[4];
#pragma unroll
  for (int ot = 0; ot < 4; ++ot) {
    float bv = bias[ot * 16 + l15];
    acc[ot] = (f32x4){bv, bv, bv, bv};
  }

  const bf16* yb = y + (size_t)b * NUP * 64;
  const int lrow = lane >> 3;                // 0..7
  const int slot = lane & 7;
  const int gw   = (slot ^ lrow) * 8;        // W pre-swizzle (srow&7 == lrow)

  bf16x8 anext[2];
  auto STAGE_W = [&](int buf, int kk) {
#pragma unroll
    for (int i = 0; i < 2; ++i) {
      int srow = wv * 16 + i * 8 + lrow;
      gload_lds16(wp + (size_t)srow * 448 + kk * 64 + gw, &lW[buf][(wv * 16 + i * 8) * 64]);
    }
  };
  auto ALOAD = [&](int kk) {
#pragma unroll
    for (int i = 0; i < 2; ++i) {
      int srow = wv * 16 + i * 8 + lrow;
      int node = nbl[srow * 7 + kk];
      anext[i] = *(const bf16x8*)(yb + (size_t)node * 64 + slot * 8);
    }
  };
  auto BNW = [&]() {
#pragma unroll
    for (int i = 0; i < 2; ++i) {
      int srow = wv * 16 + i * 8 + lrow;
      union { bf16x8 v; bf16 e[8]; } u, o_;
      u.v = anext[i];
#pragma unroll
      for (int j = 0; j < 8; ++j) {
        int c = slot * 8 + j;
        float f = __bfloat162float(u.e[j]);
        o_.e[j] = __float2bfloat16(lrelu(fmaf(f, ssc[c], ssh[c])));
      }
      *(bf16x8*)(&lA[srow * 66 + slot * 8]) = o_.v;
    }
  };

  const int r = wv * 16 + l15;

  __syncthreads();                           // nbl, ssc ready
  STAGE_W(0, 0); ALOAD(0);
  __syncthreads();                           // W(0) staged, A(0) loads drained
  BNW();

  int buf = 0;
#pragma unroll
  for (int t = 0; t < NSTEP; ++t) {
    if (t + 1 < NSTEP) { STAGE_W(buf ^ 1, t + 1); ALOAD(t + 1); }
#pragma unroll
    for (int ks = 0; ks < 2; ++ks) {
      int sa = ks * 4 + l4;
      bf16x8 a = *(const bf16x8*)(&lA[r * 66 + sa * 8]);      // padded: no XOR needed
#pragma unroll
      for (int ot = 0; ot < 4; ++ot) {
        int o = ot * 16 + l15;
        bf16x8 bb = *(const bf16x8*)(&lW[buf][o * 64 + ((sa ^ (o & 7)) * 8)]);
        acc[ot] = __builtin_amdgcn_mfma_f32_16x16x32_bf16(a, bb, acc[ot], 0, 0, 0);
      }
    }
    __syncthreads();                         // drains W-DMA(t+1) and ALOAD(t+1)
    if (t + 1 < NSTEP) BNW();                // write own rows for t+1 (wave-private)
    buf ^= 1;
  }

  float* lred = (float*)&lA[0];
  float s[4], q[4];
#pragma unroll
  for (int ot = 0; ot < 4; ++ot) { s[ot] = 0.0f; q[ot] = 0.0f; }
  bf16* yo = y2 + (size_t)b * NUP * 64;
  int nodebase = n0 + wv * 16 + l4 * 4;
#pragma unroll
  for (int i = 0; i < 4; ++i) {
    int node = nodebase + i;
    bool ok = node < NUP;
#pragma unroll
    for (int ot = 0; ot < 4; ++ot) {
      float v = acc[ot][i];
      if (ok) {
        yo[(size_t)node * 64 + ot * 16 + l15] = __float2bfloat16(v);
        s[ot] += v; q[ot] += v * v;
      }
    }
  }
#pragma unroll
  for (int ot = 0; ot < 4; ++ot) {
    s[ot] += __shfl_xor(s[ot], 16); s[ot] += __shfl_xor(s[ot], 32);
    q[ot] += __shfl_xor(q[ot], 16); q[ot] += __shfl_xor(q[ot], 32);
  }
  __syncthreads();                           // acc reads of lA done before lred overwrite
  if (lane < 16) {
#pragma unroll
    for (int ot = 0; ot < 4; ++ot) {
      lred[(wv * 2 + 0) * 64 + ot * 16 + lane] = s[ot];
      lred[(wv * 2 + 1) * 64 + ot * 16 + lane] = q[ot];
    }
  }
  __syncthreads();
  if (tid < 128) {
    int which = tid >> 6, c = tid & 63;
    float p = lred[(0 * 2 + which) * 64 + c] + lred[(1 * 2 + which) * 64 + c] +
              lred[(2 * 2 + which) * 64 + c] + lred[(3 * 2 + which) * 64 + c];
    partials[((size_t)b * gridDim.x + blockIdx.x) * 128 + which * 64 + c] = p;
  }
}

// ---------------- K4a: tree-reduce partials (nblk x 128) -> (16 x 128) -----------------------
__global__ __launch_bounds__(256) void k_red1(const float* __restrict__ p, int nblk,
                                              float* __restrict__ p2) {
  int g = blockIdx.x * 2 + threadIdx.x / 128;   // 0..15
  int j = threadIdx.x & 127;
  float a = 0.0f;
  for (int r = g; r < nblk; r += 16) a += p[(size_t)r * 128 + j];
  p2[(size_t)g * 128 + j] = a;
}

// ---------------- K4b: finalize BN: sc = g*rsqrt(var+eps), sh = beta - mean*sc ---------------
__global__ __launch_bounds__(128) void k_stats(const float* __restrict__ p2,
                                               const float* __restrict__ g,
                                               const float* __restrict__ be,
                                               float* __restrict__ sc, float* __restrict__ sh) {
  __shared__ double red[128];
  int j = threadIdx.x;
  double a = 0.0;
#pragma unroll
  for (int r = 0; r < 16; ++r) a += (double)p2[r * 128 + j];
  red[j] = a;
  __syncthreads();
  if (j < 64) {
    double M = (double)NBATCH * (double)NUP;
    double mean = red[j] / M;
    double var = red[64 + j] / M - mean * mean;
    float s = g[j] * (float)(1.0 / sqrt(var + BN_EPS));
    sc[j] = s;
    sh[j] = be[j] - (float)mean * s;
  }
}

// ---------------- K8: out[b,c,n] = lrelu(y2[b,n,c]*sc+sh)  (transpose to channel-major) ------
__global__ __launch_bounds__(256) void k_final(const bf16* __restrict__ y,
                                               const float* __restrict__ sc,
                                               const float* __restrict__ sh,
                                               float* __restrict__ out) {
  __shared__ float t[64][65];
  __shared__ float ssc[64], ssh[64];
  int tid = threadIdx.x, b = blockIdx.y;
  int n0 = blockIdx.x * 64;
  if (tid < 64) { ssc[tid] = sc[tid]; ssh[tid] = sh[tid]; }
  __syncthreads();
  int ln = tid >> 2, qc = tid & 3;
  int n = n0 + ln; if (n >= NUP) n = NUP - 1;
  const bf16* yp = y + ((size_t)b * NUP + n) * 64 + qc * 16;
  union { bf16x8 v; bf16 el[8]; } v0, v1;
  v0.v = ((const bf16x8*)yp)[0];
  v1.v = ((const bf16x8*)yp)[1];
#pragma unroll
  for (int j = 0; j < 8; ++j) {
    int c = qc * 16 + j;
    t[ln][c] = lrelu(fmaf(__bfloat162float(v0.el[j]), ssc[c], ssh[c]));
  }
#pragma unroll
  for (int j = 0; j < 8; ++j) {
    int c = qc * 16 + 8 + j;
    t[ln][c] = lrelu(fmaf(__bfloat162float(v1.el[j]), ssc[c], ssh[c]));
  }
  __syncthreads();
  int nl = tid & 63;
  int nn = n0 + nl;
  if (nn >= NUP) return;
#pragma unroll
  for (int i = 0; i < 16; ++i) {
    int c = i * 4 + (tid >> 6);
    out[((size_t)b * 64 + c) * (size_t)NUP + nn] = t[nl][c];
  }
}

extern "C" void kernel_launch(void* const* d_in, const int* in_sizes, int n_in,
                              void* d_out, int out_size, void* d_ws, size_t ws_size,
                              hipStream_t stream) {
  const float* x1      = (const float*)d_in[0];
  const float* x2      = (const float*)d_in[1];
  const float* up_fc_w = (const float*)d_in[2];
  const float* up_fc_b = (const float*)d_in[3];
  const float* conv1_w = (const float*)d_in[4];
  const float* conv1_b = (const float*)d_in[5];
  const float* bn1_g   = (const float*)d_in[6];
  const float* bn1_b   = (const float*)d_in[7];
  const float* conv2_w = (const float*)d_in[8];
  const float* conv2_b = (const float*)d_in[9];
  const float* bn2_g   = (const float*)d_in[10];
  const float* bn2_b   = (const float*)d_in[11];
  const int* up_neigh  = (const int*)d_in[12];
  const int* conv_nei  = (const int*)d_in[13];

  char* ws = (char*)d_ws;
  bf16*  w1p  = (bf16*)(ws + OFF_W1P);
  bf16*  w2p  = (bf16*)(ws + OFF_W2P);
  float* sc   = (float*)(ws + OFF_STATS);
  float* sh   = sc + 64;
  bf16*  h    = (bf16*)(ws + OFF_H);
  float* part = (float*)(ws + OFF_H);      // aliases h (h dead after k_prep)
  float* p2   = (float*)(ws + OFF_P2);
  bf16*  hm   = (bf16*)(ws + OFF_HM);
  bf16*  y2   = (bf16*)(ws + OFF_HM);      // aliases hm (dead after conv1)
  bf16*  x2t  = (bf16*)(ws + OFF_X2T);
  bf16*  y    = (bf16*)(ws + OFF_Y);
  float* out  = (float*)d_out;

  k_h<<<dim3(641 + 336, 2), 256, 0, stream>>>(x1, up_fc_w, up_fc_b, h,
                                              conv1_w, conv2_w, w1p, w2p);
  k_prep<<<dim3(NTC, 2), 256, 0, stream>>>(x2, h, up_neigh, hm, x2t);
  k_conv1<<<dim3(NTC, 2), 256, 0, stream>>>(hm, x2t, conv_nei, w1p, conv1_b, y, part);
  k_red1<<<8, 256, 0, stream>>>(part, 2 * NTC, p2);
  k_stats<<<1, 128, 0, stream>>>(p2, bn1_g, bn1_b, sc, sh);
  k_conv2<<<dim3(NTC, 2), 256, 0, stream>>>(y, conv_nei, w2p, conv2_b, sc, sh, y2, part);
  k_red1<<<8, 256, 0, stream>>>(part, 2 * NTC, p2);
  k_stats<<<1, 128, 0, stream>>>(p2, bn2_g, bn2_b, sc, sh);
  k_final<<<dim3(NTC, 2), 256, 0, stream>>>(y2, sc, sh, out);
}

// Round 11
// 333.345 us; speedup vs baseline: 1.3743x; 1.3743x over previous
//
#include <hip/hip_runtime.h>
#include <hip/hip_bf16.h>

typedef __hip_bfloat16 bf16;
typedef short bf16x8 __attribute__((ext_vector_type(8)));   // 8 bf16 = 16B (4 VGPRs)
typedef float f32x4 __attribute__((ext_vector_type(4)));

#define ND     40962
#define NUP    163842
#define NBATCH 2
#define NTC    2561            // ceil(NUP/64)
#define BN_EPS 1e-5
#define SLOPE  0.2f

// ---- ws layout (bytes) ----
#define OFF_W1P   0ull                      // 64*896*2  = 114688
#define OFF_W2P   114688ull                 // 64*448*2  = 57344
#define OFF_STATS 172032ull                 // sc[64]+sh[64] fp32
#define OFF_H     173056ull                 // h bf16: 2*40962*64*2 = 10486272 ; partials alias
#define OFF_P2    (OFF_H + 2622464ull)      // p2 (64KB) aliases h tail
#define OFF_HM    10659328ull               // hm bf16: 2*163842*64*2 = 41943552 ; y2 aliases
#define OFF_X2T   52602880ull               // x2t bf16: 41943552
#define OFF_Y     94546432ull               // y bf16: 41943552
// total ≈ 136.5 MB

__device__ __forceinline__ void gload_lds16(const void* g, void* l) {
  __builtin_amdgcn_global_load_lds(
      (const __attribute__((address_space(1))) void*)g,
      (__attribute__((address_space(3))) void*)l, 16, 0, 0);
}

__device__ __forceinline__ float lrelu(float v) { return v >= 0.0f ? v : SLOPE * v; }

// ---------------- K0: permute + bf16-convert conv weights: f' = kk*C + c ----------------
__global__ __launch_bounds__(256) void k_permw(const float* __restrict__ w1,
                                               const float* __restrict__ w2,
                                               bf16* __restrict__ w1p, bf16* __restrict__ w2p) {
  int t = blockIdx.x * 256 + threadIdx.x;
  if (t < 64 * 896) {
    int o = t / 896, f = t % 896;
    int kk = f / 128, c = f % 128;
    w1p[t] = __float2bfloat16(w1[o * 896 + c * 7 + kk]);
  } else if (t < 64 * 896 + 64 * 448) {
    int idx = t - 64 * 896;
    int o = idx / 448, f = idx % 448;
    int kk = f / 64, c = f % 64;
    w2p[idx] = __float2bfloat16(w2[o * 448 + c * 7 + kk]);
  }
}

// ---------------- K1: h[b,n,o] (bf16 node-major). 64 nodes/block, 16 outs/thread -------------
__global__ __launch_bounds__(256) void k_h(const float* __restrict__ x1,
                                           const float* __restrict__ wfc,
                                           const float* __restrict__ bfc,
                                           bf16* __restrict__ h) {
  __shared__ float wl[128 * 64];   // wl[c*64+o]
  __shared__ float bl[64];
  int tid = threadIdx.x, b = blockIdx.y;
  for (int i = tid; i < 8192; i += 256) { int o = i >> 7, c = i & 127; wl[c * 64 + o] = wfc[i]; }
  if (tid < 64) bl[tid] = bfc[tid];
  __syncthreads();
  int ln = tid & 63, wv = tid >> 6;          // node-lane, out-group (wave-uniform)
  int n = blockIdx.x * 64 + ln;
  int nc = n < ND ? n : ND - 1;
  float acc[16];
#pragma unroll
  for (int j = 0; j < 16; ++j) acc[j] = bl[wv * 16 + j];
#pragma unroll 4
  for (int c = 0; c < 128; ++c) {
    float xv = x1[((size_t)b * 128 + c) * (size_t)ND + nc];
    const f32x4* wrow = (const f32x4*)(wl + c * 64 + wv * 16);   // wave-uniform -> broadcast
#pragma unroll
    for (int g = 0; g < 4; ++g) {
      f32x4 wvv = wrow[g];
      acc[g * 4 + 0] = fmaf(xv, wvv[0], acc[g * 4 + 0]);
      acc[g * 4 + 1] = fmaf(xv, wvv[1], acc[g * 4 + 1]);
      acc[g * 4 + 2] = fmaf(xv, wvv[2], acc[g * 4 + 2]);
      acc[g * 4 + 3] = fmaf(xv, wvv[3], acc[g * 4 + 3]);
    }
  }
  if (n < ND) {
    bf16* hp = h + ((size_t)b * ND + n) * 64 + wv * 16;
#pragma unroll
    for (int og = 0; og < 2; ++og) {
      union { bf16x8 v; bf16 e[8]; } u;
#pragma unroll
      for (int j = 0; j < 8; ++j) u.e[j] = __float2bfloat16(acc[og * 8 + j]);
      ((bf16x8*)hp)[og] = u.v;
    }
  }
}

// ---------------- K2: prep — hm[b,m,:]=0.5*(h[up0]+h[up1]) AND x2t[b,m,c]=bf16(x2[b,c,m]) ----
__global__ __launch_bounds__(256) void k_prep(const float* __restrict__ x2,
                                              const bf16* __restrict__ h,
                                              const int* __restrict__ upn,
                                              bf16* __restrict__ hm,
                                              bf16* __restrict__ x2t) {
  __shared__ float tt[64][65];
  __shared__ int un[64][2];
  int tid = threadIdx.x, b = blockIdx.y;
  int m0 = blockIdx.x * 64;
#pragma unroll
  for (int i = 0; i < 16; ++i) {
    int c = i * 4 + (tid >> 6);
    int ml = tid & 63;
    int m = m0 + ml; if (m >= NUP) m = NUP - 1;
    tt[c][ml] = x2[((size_t)b * 64 + c) * (size_t)NUP + m];
  }
  if (tid < 128) {
    int ml = tid >> 1, w = tid & 1;
    int m = m0 + ml; if (m >= NUP) m = NUP - 1;
    un[ml][w] = upn[(size_t)m * 2 + w];
  }
  __syncthreads();
  int ln = tid >> 2, p = tid & 3;            // 4 threads per node, 32B seg each
  int m = m0 + ln;
  if (m >= NUP) return;
  // hm part
  {
    const bf16* h0 = h + ((size_t)b * ND + un[ln][0]) * 64 + p * 16;
    const bf16* h1 = h + ((size_t)b * ND + un[ln][1]) * 64 + p * 16;
    bf16* d = hm + ((size_t)b * NUP + m) * 64 + p * 16;
#pragma unroll
    for (int q = 0; q < 2; ++q) {
      union { bf16x8 v; bf16 e[8]; } a, bb, o_;
      a.v = ((const bf16x8*)h0)[q];
      bb.v = ((const bf16x8*)h1)[q];
#pragma unroll
      for (int j = 0; j < 8; ++j)
        o_.e[j] = __float2bfloat16(0.5f * (__bfloat162float(a.e[j]) + __bfloat162float(bb.e[j])));
      ((bf16x8*)d)[q] = o_.v;
    }
  }
  // x2t part
  {
    bf16* d = x2t + ((size_t)b * NUP + m) * 64 + p * 16;
#pragma unroll
    for (int q = 0; q < 2; ++q) {
      union { bf16x8 v; bf16 e[8]; } o_;
#pragma unroll
      for (int j = 0; j < 8; ++j) o_.e[j] = __float2bfloat16(tt[p * 16 + q * 8 + j][ln]);
      ((bf16x8*)d)[q] = o_.v;
    }
  }
}

// ---------------- K3: conv1 — 64ch (128B-row) steps, A+W DMA dbuf, 1 barrier/step ------------
// Step t: kk = t>>1, half = t&1 (0 -> hm, 1 -> x2t). Requests are 8-lane 128B (L2 line).
__global__ __launch_bounds__(256, 4) void k_conv1(const bf16* __restrict__ hm,
                                                  const bf16* __restrict__ x2t,
                                                  const int* __restrict__ neigh,
                                                  const bf16* __restrict__ wp,
                                                  const float* __restrict__ bias,
                                                  bf16* __restrict__ y,
                                                  float* __restrict__ partials) {
  constexpr int NSTEP = 14;
  __shared__ bf16 lA[2][64 * 64];            // 8KB each
  __shared__ bf16 lW[2][64 * 64];
  __shared__ int nbl[448];

  int tid = threadIdx.x, b = blockIdx.y;
  int n0 = blockIdx.x * 64;
  int wv = tid >> 6, lane = tid & 63;
  int l15 = lane & 15, l4 = lane >> 4;

  for (int j = tid; j < 448; j += 256) {
    int gi = n0 * 7 + j;
    int gmax = NUP * 7 - 1;
    nbl[j] = neigh[gi <= gmax ? gi : gmax];
  }

  f32x4 acc[4];
#pragma unroll
  for (int ot = 0; ot < 4; ++ot) {
    float bv = bias[ot * 16 + l15];
    acc[ot] = (f32x4){bv, bv, bv, bv};
  }

  const bf16* hmb  = hm  + (size_t)b * NUP * 64;
  const bf16* x2tb = x2t + (size_t)b * NUP * 64;
  const int lrow = lane >> 3;                // row within instr
  const int g    = ((lane & 7) ^ lrow) * 8;  // pre-swizzled slot (elems), row&7 == lrow

  auto STAGE = [&](int buf, int t) {
    int kk = t >> 1;
    const bf16* src = (t & 1) ? x2tb : hmb;
#pragma unroll
    for (int i = 0; i < 2; ++i) {
      int srow = wv * 16 + i * 8 + lrow;
      int node = nbl[srow * 7 + kk];
      gload_lds16(src + (size_t)node * 64 + g, &lA[buf][(wv * 16 + i * 8) * 64]);
      gload_lds16(wp + (size_t)srow * 896 + t * 64 + g, &lW[buf][(wv * 16 + i * 8) * 64]);
    }
  };

  const int r = wv * 16 + l15;

  __syncthreads();                           // nbl ready
  STAGE(0, 0);
  __syncthreads();                           // step 0 staged (implicit vmcnt(0))

  int buf = 0;
#pragma unroll
  for (int t = 0; t < NSTEP; ++t) {
    if (t + 1 < NSTEP) STAGE(buf ^ 1, t + 1);
#pragma unroll
    for (int ks = 0; ks < 2; ++ks) {
      int sa = ks * 4 + l4;                  // 0..7
      bf16x8 a = *(const bf16x8*)(&lA[buf][r * 64 + ((sa ^ (r & 7)) * 8)]);
#pragma unroll
      for (int ot = 0; ot < 4; ++ot) {
        int o = ot * 16 + l15;
        bf16x8 bb = *(const bf16x8*)(&lW[buf][o * 64 + ((sa ^ (o & 7)) * 8)]);
        acc[ot] = __builtin_amdgcn_mfma_f32_16x16x32_bf16(a, bb, acc[ot], 0, 0, 0);
      }
    }
    __syncthreads();
    buf ^= 1;
  }

  float* lred = (float*)&lA[0][0];
  float s[4], q[4];
#pragma unroll
  for (int ot = 0; ot < 4; ++ot) { s[ot] = 0.0f; q[ot] = 0.0f; }
  bf16* yb = y + (size_t)b * NUP * 64;
  int nodebase = n0 + wv * 16 + l4 * 4;
#pragma unroll
  for (int i = 0; i < 4; ++i) {
    int node = nodebase + i;
    bool ok = node < NUP;
#pragma unroll
    for (int ot = 0; ot < 4; ++ot) {
      float v = acc[ot][i];
      if (ok) {
        yb[(size_t)node * 64 + ot * 16 + l15] = __float2bfloat16(v);
        s[ot] += v; q[ot] += v * v;
      }
    }
  }
#pragma unroll
  for (int ot = 0; ot < 4; ++ot) {
    s[ot] += __shfl_xor(s[ot], 16); s[ot] += __shfl_xor(s[ot], 32);
    q[ot] += __shfl_xor(q[ot], 16); q[ot] += __shfl_xor(q[ot], 32);
  }
  if (lane < 16) {
#pragma unroll
    for (int ot = 0; ot < 4; ++ot) {
      lred[(wv * 2 + 0) * 64 + ot * 16 + lane] = s[ot];
      lred[(wv * 2 + 1) * 64 + ot * 16 + lane] = q[ot];
    }
  }
  __syncthreads();
  if (tid < 128) {
    int which = tid >> 6, c = tid & 63;
    float p = lred[(0 * 2 + which) * 64 + c] + lred[(1 * 2 + which) * 64 + c] +
              lred[(2 * 2 + which) * 64 + c] + lred[(3 * 2 + which) * 64 + c];
    partials[((size_t)b * gridDim.x + blockIdx.x) * 128 + which * 64 + c] = p;
  }
}

// ---------------- K5: conv2 — full-kk steps; BN1+lrelu fused reg-staged A (padded, 1-buf) ----
__global__ __launch_bounds__(256, 6) void k_conv2(const bf16* __restrict__ y,
                                                  const int* __restrict__ neigh,
                                                  const bf16* __restrict__ wp,
                                                  const float* __restrict__ bias,
                                                  const float* __restrict__ sc,
                                                  const float* __restrict__ sh,
                                                  bf16* __restrict__ y2,
                                                  float* __restrict__ partials) {
  constexpr int NSTEP = 7;
  __shared__ bf16 lA[64 * 66];               // padded rows: stride 132B
  __shared__ bf16 lW[2][64 * 64];
  __shared__ int nbl[448];
  __shared__ float ssc[64], ssh[64];

  int tid = threadIdx.x, b = blockIdx.y;
  int n0 = blockIdx.x * 64;
  int wv = tid >> 6, lane = tid & 63;
  int l15 = lane & 15, l4 = lane >> 4;

  for (int j = tid; j < 448; j += 256) {
    int gi = n0 * 7 + j;
    int gmax = NUP * 7 - 1;
    nbl[j] = neigh[gi <= gmax ? gi : gmax];
  }
  if (tid < 64) { ssc[tid] = sc[tid]; ssh[tid] = sh[tid]; }

  f32x4 acc[4];
#pragma unroll
  for (int ot = 0; ot < 4; ++ot) {
    float bv = bias[ot * 16 + l15];
    acc[ot] = (f32x4){bv, bv, bv, bv};
  }

  const bf16* yb = y + (size_t)b * NUP * 64;
  const int lrow = lane >> 3;                // 0..7
  const int slot = lane & 7;
  const int gw   = (slot ^ lrow) * 8;        // W pre-swizzle (srow&7 == lrow)

  bf16x8 anext[2];
  auto STAGE_W = [&](int buf, int kk) {
#pragma unroll
    for (int i = 0; i < 2; ++i) {
      int srow = wv * 16 + i * 8 + lrow;
      gload_lds16(wp + (size_t)srow * 448 + kk * 64 + gw, &lW[buf][(wv * 16 + i * 8) * 64]);
    }
  };
  auto ALOAD = [&](int kk) {
#pragma unroll
    for (int i = 0; i < 2; ++i) {
      int srow = wv * 16 + i * 8 + lrow;
      int node = nbl[srow * 7 + kk];
      anext[i] = *(const bf16x8*)(yb + (size_t)node * 64 + slot * 8);
    }
  };
  auto BNW = [&]() {
#pragma unroll
    for (int i = 0; i < 2; ++i) {
      int srow = wv * 16 + i * 8 + lrow;
      union { bf16x8 v; bf16 e[8]; } u, o_;
      u.v = anext[i];
#pragma unroll
      for (int j = 0; j < 8; ++j) {
        int c = slot * 8 + j;
        float f = __bfloat162float(u.e[j]);
        o_.e[j] = __float2bfloat16(lrelu(fmaf(f, ssc[c], ssh[c])));
      }
      *(bf16x8*)(&lA[srow * 66 + slot * 8]) = o_.v;
    }
  };

  const int r = wv * 16 + l15;

  __syncthreads();                           // nbl, ssc ready
  STAGE_W(0, 0); ALOAD(0);
  __syncthreads();                           // W(0) staged, A(0) loads drained
  BNW();

  int buf = 0;
#pragma unroll
  for (int t = 0; t < NSTEP; ++t) {
    if (t + 1 < NSTEP) { STAGE_W(buf ^ 1, t + 1); ALOAD(t + 1); }
#pragma unroll
    for (int ks = 0; ks < 2; ++ks) {
      int sa = ks * 4 + l4;
      bf16x8 a = *(const bf16x8*)(&lA[r * 66 + sa * 8]);      // padded: no XOR needed
#pragma unroll
      for (int ot = 0; ot < 4; ++ot) {
        int o = ot * 16 + l15;
        bf16x8 bb = *(const bf16x8*)(&lW[buf][o * 64 + ((sa ^ (o & 7)) * 8)]);
        acc[ot] = __builtin_amdgcn_mfma_f32_16x16x32_bf16(a, bb, acc[ot], 0, 0, 0);
      }
    }
    __syncthreads();                         // drains W-DMA(t+1) and ALOAD(t+1)
    if (t + 1 < NSTEP) BNW();                // write own rows for t+1 (wave-private)
    buf ^= 1;
  }

  float* lred = (float*)&lA[0];
  float s[4], q[4];
#pragma unroll
  for (int ot = 0; ot < 4; ++ot) { s[ot] = 0.0f; q[ot] = 0.0f; }
  bf16* yo = y2 + (size_t)b * NUP * 64;
  int nodebase = n0 + wv * 16 + l4 * 4;
#pragma unroll
  for (int i = 0; i < 4; ++i) {
    int node = nodebase + i;
    bool ok = node < NUP;
#pragma unroll
    for (int ot = 0; ot < 4; ++ot) {
      float v = acc[ot][i];
      if (ok) {
        yo[(size_t)node * 64 + ot * 16 + l15] = __float2bfloat16(v);
        s[ot] += v; q[ot] += v * v;
      }
    }
  }
#pragma unroll
  for (int ot = 0; ot < 4; ++ot) {
    s[ot] += __shfl_xor(s[ot], 16); s[ot] += __shfl_xor(s[ot], 32);
    q[ot] += __shfl_xor(q[ot], 16); q[ot] += __shfl_xor(q[ot], 32);
  }
  __syncthreads();                           // acc reads of lA done before lred overwrite
  if (lane < 16) {
#pragma unroll
    for (int ot = 0; ot < 4; ++ot) {
      lred[(wv * 2 + 0) * 64 + ot * 16 + lane] = s[ot];
      lred[(wv * 2 + 1) * 64 + ot * 16 + lane] = q[ot];
    }
  }
  __syncthreads();
  if (tid < 128) {
    int which = tid >> 6, c = tid & 63;
    float p = lred[(0 * 2 + which) * 64 + c] + lred[(1 * 2 + which) * 64 + c] +
              lred[(2 * 2 + which) * 64 + c] + lred[(3 * 2 + which) * 64 + c];
    partials[((size_t)b * gridDim.x + blockIdx.x) * 128 + which * 64 + c] = p;
  }
}

// ---------------- K4a: tree-reduce partials (nblk x 128) -> (128 x 128) ----------------------
__global__ __launch_bounds__(256) void k_red1(const float* __restrict__ p, int nblk,
                                              float* __restrict__ p2) {
  int g = blockIdx.x * 2 + threadIdx.x / 128;
  int j = threadIdx.x & 127;
  float a = 0.0f;
  for (int r = g; r < nblk; r += 128) a += p[(size_t)r * 128 + j];
  p2[(size_t)g * 128 + j] = a;
}

// ---------------- K4b: finalize BN: sc = g*rsqrt(var+eps), sh = beta - mean*sc ---------------
__global__ __launch_bounds__(128) void k_stats(const float* __restrict__ p2,
                                               const float* __restrict__ g,
                                               const float* __restrict__ be,
                                               float* __restrict__ sc, float* __restrict__ sh) {
  __shared__ double red[128];
  int j = threadIdx.x;
  double a = 0.0;
  for (int r = 0; r < 128; ++r) a += (double)p2[r * 128 + j];
  red[j] = a;
  __syncthreads();
  if (j < 64) {
    double M = (double)NBATCH * (double)NUP;
    double mean = red[j] / M;
    double var = red[64 + j] / M - mean * mean;
    float s = g[j] * (float)(1.0 / sqrt(var + BN_EPS));
    sc[j] = s;
    sh[j] = be[j] - (float)mean * s;
  }
}

// ---------------- K8: out[b,c,n] = lrelu(y2[b,n,c]*sc+sh)  (transpose to channel-major) ------
__global__ __launch_bounds__(256) void k_final(const bf16* __restrict__ y,
                                               const float* __restrict__ sc,
                                               const float* __restrict__ sh,
                                               float* __restrict__ out) {
  __shared__ float t[64][65];
  __shared__ float ssc[64], ssh[64];
  int tid = threadIdx.x, b = blockIdx.y;
  int n0 = blockIdx.x * 64;
  if (tid < 64) { ssc[tid] = sc[tid]; ssh[tid] = sh[tid]; }
  __syncthreads();
  int ln = tid >> 2, qc = tid & 3;
  int n = n0 + ln; if (n >= NUP) n = NUP - 1;
  const bf16* yp = y + ((size_t)b * NUP + n) * 64 + qc * 16;
  union { bf16x8 v; bf16 el[8]; } v0, v1;
  v0.v = ((const bf16x8*)yp)[0];
  v1.v = ((const bf16x8*)yp)[1];
#pragma unroll
  for (int j = 0; j < 8; ++j) {
    int c = qc * 16 + j;
    t[ln][c] = lrelu(fmaf(__bfloat162float(v0.el[j]), ssc[c], ssh[c]));
  }
#pragma unroll
  for (int j = 0; j < 8; ++j) {
    int c = qc * 16 + 8 + j;
    t[ln][c] = lrelu(fmaf(__bfloat162float(v1.el[j]), ssc[c], ssh[c]));
  }
  __syncthreads();
  int nl = tid & 63;
  int nn = n0 + nl;
  if (nn >= NUP) return;
#pragma unroll
  for (int i = 0; i < 16; ++i) {
    int c = i * 4 + (tid >> 6);
    out[((size_t)b * 64 + c) * (size_t)NUP + nn] = t[nl][c];
  }
}

extern "C" void kernel_launch(void* const* d_in, const int* in_sizes, int n_in,
                              void* d_out, int out_size, void* d_ws, size_t ws_size,
                              hipStream_t stream) {
  const float* x1      = (const float*)d_in[0];
  const float* x2      = (const float*)d_in[1];
  const float* up_fc_w = (const float*)d_in[2];
  const float* up_fc_b = (const float*)d_in[3];
  const float* conv1_w = (const float*)d_in[4];
  const float* conv1_b = (const float*)d_in[5];
  const float* bn1_g   = (const float*)d_in[6];
  const float* bn1_b   = (const float*)d_in[7];
  const float* conv2_w = (const float*)d_in[8];
  const float* conv2_b = (const float*)d_in[9];
  const float* bn2_g   = (const float*)d_in[10];
  const float* bn2_b   = (const float*)d_in[11];
  const int* up_neigh  = (const int*)d_in[12];
  const int* conv_nei  = (const int*)d_in[13];

  char* ws = (char*)d_ws;
  bf16*  w1p  = (bf16*)(ws + OFF_W1P);
  bf16*  w2p  = (bf16*)(ws + OFF_W2P);
  float* sc   = (float*)(ws + OFF_STATS);
  float* sh   = sc + 64;
  bf16*  h    = (bf16*)(ws + OFF_H);
  float* part = (float*)(ws + OFF_H);      // aliases h (h dead after k_prep)
  float* p2   = (float*)(ws + OFF_P2);
  bf16*  hm   = (bf16*)(ws + OFF_HM);
  bf16*  y2   = (bf16*)(ws + OFF_HM);      // aliases hm (dead after conv1)
  bf16*  x2t  = (bf16*)(ws + OFF_X2T);
  bf16*  y    = (bf16*)(ws + OFF_Y);
  float* out  = (float*)d_out;

  k_permw<<<336, 256, 0, stream>>>(conv1_w, conv2_w, w1p, w2p);
  k_h<<<dim3(641, 2), 256, 0, stream>>>(x1, up_fc_w, up_fc_b, h);
  k_prep<<<dim3(NTC, 2), 256, 0, stream>>>(x2, h, up_neigh, hm, x2t);
  k_conv1<<<dim3(NTC, 2), 256, 0, stream>>>(hm, x2t, conv_nei, w1p, conv1_b, y, part);
  k_red1<<<64, 256, 0, stream>>>(part, 2 * NTC, p2);
  k_stats<<<1, 128, 0, stream>>>(p2, bn1_g, bn1_b, sc, sh);
  k_conv2<<<dim3(NTC, 2), 256, 0, stream>>>(y, conv_nei, w2p, conv2_b, sc, sh, y2, part);
  k_red1<<<64, 256, 0, stream>>>(part, 2 * NTC, p2);
  k_stats<<<1, 128, 0, stream>>>(p2, bn2_g, bn2_b, sc, sh);
  k_final<<<dim3(NTC, 2), 256, 0, stream>>>(y2, sc, sh, out);
}